// Round 6
// baseline (108.737 us; speedup 1.0000x reference)
//
#include <hip/hip_runtime.h>

#define K_DIM 131072
#define NROW 256
#define KC 512
#define BK 32
#define NS 16
#define SPLIT 256
#define TPB 1024
#define TEMP 14.285714285714286f

typedef float f32x4 __attribute__((ext_vector_type(4)));
typedef short s16x8 __attribute__((ext_vector_type(8)));
typedef unsigned int u32;
typedef u32 u32x4 __attribute__((ext_vector_type(4)));

typedef const __attribute__((address_space(1))) void gvoid;
typedef __attribute__((address_space(3))) void lvoid;

__device__ __forceinline__ u32 cvt_pk_bf16(float lo, float hi) {
    u32 r;
    asm("v_cvt_pk_bf16_f32 %0, %1, %2" : "=v"(r) : "v"(lo), "v"(hi));
    return r;
}

// Stage 1: split-K GEMM. Block pair (g, g+256) shares k-chunk k=g&255; h=g>>8
// picks the A-row half. Same (g%8) -> same XCD, co-resident at 2 blocks/CU ->
// sibling's duplicate B read hits L2/L3 within a tile-time.
// 16 waves as 8x2: wave strip = 16 rows x 128 cols -> acc = 8 x f32x4 = 32 VGPR.
// A: fp32 LDS via global_load_lds (linear dest, involution source-swizzle).
// B: register-staged, cvt to bf16, LDS rows padded to 80 B (bank-spread, b128-aligned).
__global__ __launch_bounds__(TPB, 8) void gemm_pair(
    const float* __restrict__ A, const float* __restrict__ Bm,
    float* __restrict__ partials)
{
    __shared__ __align__(16) float As[2][128 * BK];            // 16 KB per buf
    __shared__ __align__(16) unsigned short Bs[2][256 * 40];   // 20 KB per buf

    const int g = blockIdx.x;
    const int k = g & 255;
    const int h = g >> 8;

    const int t    = threadIdx.x;
    const int lane = t & 63;
    const int w    = t >> 6;          // 0..15
    const int wr   = (w >> 1) * 16;   // wave row base within 128-half
    const int wc   = (w & 1) * 128;   // wave col base

    // ---- A staging: wave w stages rows [8w, 8w+8) of the half; 1 gload/tile.
    // LDS dest linear (HW: uniform base + lane*16); source chunk = (l&7)^(l>>3)
    // so LDS[row][c] holds global chunk c^(row&7) (involution).
    const int adrow = lane >> 3;            // 0..7
    const int asch  = (lane & 7) ^ adrow;   // swizzled source 16B-chunk
    const float* aSrc = A + (long)(h * 128 + w * 8 + adrow) * K_DIM
                          + (long)k * KC + asch * 4;

    // ---- B staging (regs): thread t -> row t>>2, f32 cols (t&3)*8 .. +8
    const int brow = t >> 2;
    const float* bSrc = Bm + (long)brow * K_DIM + (long)k * KC + (t & 3) * 8;
    char* const bDst0 = (char*)&Bs[0][0] + brow * 80 + (t & 3) * 16;
    char* const bDst1 = (char*)&Bs[1][0] + brow * 80 + (t & 3) * 16;

    // ---- fragment-read constants
    const int arow  = wr + (lane & 15);
    const int aoff0 = arow * 128 + ((((lane >> 4) * 2)     ^ (arow & 7)) * 16);
    const int aoff1 = arow * 128 + ((((lane >> 4) * 2 + 1) ^ (arow & 7)) * 16);
    const int bbase = (wc + (lane & 15)) * 80 + (lane >> 4) * 16;  // + n*1280

    f32x4 acc[8];
#pragma unroll
    for (int n = 0; n < 8; ++n) acc[n] = f32x4{0.f, 0.f, 0.f, 0.f};

    // prologue: A(0) gload + B(0) register loads
    __builtin_amdgcn_global_load_lds((gvoid*)aSrc,
        (lvoid*)&As[0][w * 256], 16, 0, 0);
    f32x4 bv0 = *(const f32x4*)(bSrc);
    f32x4 bv1 = *(const f32x4*)(bSrc + 4);

#pragma unroll
    for (int T = 0; T < NS; ++T) {
        const int buf = T & 1;

        // cvt + publish B(T) into Bs[buf]
        u32x4 bw;
        bw[0] = cvt_pk_bf16(bv0.x, bv0.y);
        bw[1] = cvt_pk_bf16(bv0.z, bv0.w);
        bw[2] = cvt_pk_bf16(bv1.x, bv1.y);
        bw[3] = cvt_pk_bf16(bv1.z, bv1.w);
        *(u32x4*)(buf ? bDst1 : bDst0) = bw;

        // drain A(T) gload + my ds_write, then publish to the block
        asm volatile("s_waitcnt vmcnt(0) lgkmcnt(0)" ::: "memory");
        __builtin_amdgcn_s_barrier();

        // issue next tile's loads; they land during compute + barriers
        if (T + 1 < NS) {
            __builtin_amdgcn_global_load_lds((gvoid*)(aSrc + (T + 1) * BK),
                (lvoid*)&As[buf ^ 1][w * 256], 16, 0, 0);
            bv0 = *(const f32x4*)(bSrc + (T + 1) * BK);
            bv1 = *(const f32x4*)(bSrc + (T + 1) * BK + 4);
        }

        // A fragment: swizzled fp32 read + cvt to bf16
        const char* ab = (const char*)&As[buf][0];
        f32x4 alo = *(const f32x4*)(ab + aoff0);
        f32x4 ahi = *(const f32x4*)(ab + aoff1);
        union { u32 u[4]; s16x8 s; } afu;
        afu.u[0] = cvt_pk_bf16(alo.x, alo.y);
        afu.u[1] = cvt_pk_bf16(alo.z, alo.w);
        afu.u[2] = cvt_pk_bf16(ahi.x, ahi.y);
        afu.u[3] = cvt_pk_bf16(ahi.z, ahi.w);
        const s16x8 af = afu.s;

        const char* bb = (const char*)&Bs[buf][0];
#pragma unroll
        for (int n = 0; n < 8; ++n) {
            s16x8 bf = *(const s16x8*)(bb + bbase + n * 1280);
            acc[n] = __builtin_amdgcn_mfma_f32_16x16x32_bf16(af, bf, acc[n], 0, 0, 0);
        }

        // all my LDS reads retired, then free both buffers for next writes
        asm volatile("s_waitcnt lgkmcnt(0)" ::: "memory");
        __builtin_amdgcn_s_barrier();
    }

    // epilogue: C/D map col=lane&15, row=(lane>>4)*4+j (16x16 shape)
    float* outp = partials + (size_t)k * (NROW * NROW);
    const int crow0 = h * 128 + wr + (lane >> 4) * 4;
    const int ccol0 = wc + (lane & 15);
#pragma unroll
    for (int n = 0; n < 8; ++n) {
#pragma unroll
        for (int j = 0; j < 4; ++j) {
            __builtin_nontemporal_store(acc[n][j],
                outp + (size_t)(crow0 + j) * NROW + ccol0 + 16 * n);
        }
    }
}

// Stage 2: reduce partials over split; per-row masked exp, rowsum, pos, rowloss; store E.
__global__ __launch_bounds__(NROW) void reduce_loss_rows(
    const float* __restrict__ partials, const int* __restrict__ idx,
    float* __restrict__ E, float* __restrict__ rowloss, float* __restrict__ posbuf)
{
    const int b = blockIdx.x;   // row
    const int t = threadIdx.x;  // col
    const float* p = partials + b * NROW + t;
    float sum = 0.f;
#pragma unroll 8
    for (int s = 0; s < SPLIT; ++s)
        sum += p[(size_t)s * (NROW * NROW)];

    const float logit = sum * TEMP;
    const bool  mask  = (idx[b] != idx[t]) || (b == t);
    const float e     = mask ? expf(logit) : 0.0f;
    E[b * NROW + t] = e;

    __shared__ float red[NROW];
    __shared__ float posv;
    if (t == b) posv = logit;
    red[t] = e;
    __syncthreads();
#pragma unroll
    for (int s = NROW / 2; s > 0; s >>= 1) {
        if (t < s) red[t] += red[t + s];
        __syncthreads();
    }
    if (t == 0) {
        posbuf[b]  = posv;
        rowloss[b] = logf(red[0]) - posv;
    }
}

// Stage 3: column sums of E, column losses, final mean.
__global__ __launch_bounds__(NROW) void finalize_loss(
    const float* __restrict__ E, const float* __restrict__ rowloss,
    const float* __restrict__ posbuf, float* __restrict__ out)
{
    const int t = threadIdx.x;
    float csum = 0.f;
#pragma unroll 8
    for (int i = 0; i < NROW; ++i)
        csum += E[i * NROW + t];
    const float closs = logf(csum) - posbuf[t];
    const float rl    = rowloss[t];

    __shared__ float redc[NROW];
    __shared__ float redr[NROW];
    redc[t] = closs;
    redr[t] = rl;
    __syncthreads();
#pragma unroll
    for (int s = NROW / 2; s > 0; s >>= 1) {
        if (t < s) { redc[t] += redc[t + s]; redr[t] += redr[t + s]; }
        __syncthreads();
    }
    if (t == 0)
        out[0] = 0.5f * (redc[0] + redr[0]) * (1.0f / (float)NROW);
}

extern "C" void kernel_launch(void* const* d_in, const int* in_sizes, int n_in,
                              void* d_out, int out_size, void* d_ws, size_t ws_size,
                              hipStream_t stream)
{
    (void)in_sizes; (void)n_in; (void)out_size; (void)ws_size;
    const float* A   = (const float*)d_in[0];
    const float* Bm  = (const float*)d_in[1];
    const int*   idx = (const int*)d_in[2];
    float*       out = (float*)d_out;

    float* partials = (float*)d_ws;                       // 64 MB (split=256)
    float* E        = partials + (size_t)SPLIT * NROW * NROW;
    float* rowloss  = E + NROW * NROW;
    float* posbuf   = rowloss + NROW;

    gemm_pair<<<SPLIT * 2, TPB, 0, stream>>>(A, Bm, partials);
    reduce_loss_rows<<<NROW, NROW, 0, stream>>>(partials, idx, E, rowloss, posbuf);
    finalize_loss<<<1, NROW, 0, stream>>>(E, rowloss, posbuf, out);
}

// Round 7
// 106.543 us; speedup vs baseline: 1.0206x; 1.0206x over previous
//
#include <hip/hip_runtime.h>

#define K_DIM 131072
#define NROW 256
#define KC 512
#define BK 32
#define NS 16              // KC / BK
#define SPLIT 256
#define TPB 512
#define TEMP 14.285714285714286f
#define ROWB 80            // padded LDS row bytes (40 shorts): 4-way banks max

typedef float f32x4  __attribute__((ext_vector_type(4)));
typedef float f32x16 __attribute__((ext_vector_type(16)));
typedef short s16x8  __attribute__((ext_vector_type(8)));
typedef unsigned int u32;

__device__ __forceinline__ u32 cvt_pk_bf16(float lo, float hi) {
    u32 r;
    asm("v_cvt_pk_bf16_f32 %0, %1, %2" : "=v"(r) : "v"(lo), "v"(hi));
    return r;
}

// Stage 1: split-K GEMM, half-C (128x256) per block. Pair (g, g+256) shares
// k-chunk g&255 -> same XCD (256%8==0) and co-resident (grid 512 = 2/CU), so
// the pair's duplicate B read hits L2. A is read exactly once.
// R2-proven pipeline: register-staged globals (compiler-scheduled vmcnt),
// cvt_pk -> bf16 LDS (80-B padded rows), single buffer, lgkm-only barriers.
// 8 waves as 2x4, wave tile 64x64 = 2x2 MFMA 32x32x16, acc 64 VGPR.
__global__ __launch_bounds__(TPB, 4) void gemm_half2(
    const float* __restrict__ A, const float* __restrict__ Bm,
    float* __restrict__ partials)
{
    __shared__ __align__(16) unsigned short As[128 * (ROWB / 2)];  // 10 KB
    __shared__ __align__(16) unsigned short Bs[256 * (ROWB / 2)];  // 20 KB

    const int g = blockIdx.x;
    const int k = g & 255;
    const int h = g >> 8;

    const int t    = threadIdx.x;
    const int lane = t & 63;
    const int w    = t >> 6;          // 0..7
    const int wm   = (w >> 2) * 64;   // wave row base within half
    const int wn   = (w & 3) * 64;    // wave col base

    // ---- staging: thread -> row t>>3 (8 lanes/row, 16 B/lane: 4 lines/wave-instr)
    const int srow = t >> 3;          // 0..63
    const int scol = (t & 7) * 4;     // f32 col within BK

    const float* aBase = A  + (long)(h * 128 + srow) * K_DIM + (long)k * KC + scol;
    const float* bBase = Bm + (long)srow              * K_DIM + (long)k * KC + scol;
    const long rstep = 64L * K_DIM;

    char* const aW0 = (char*)As + srow * ROWB + (t & 7) * 8;
    char* const aW1 = aW0 + 64 * ROWB;
    char* const bW0 = (char*)Bs + srow * ROWB + (t & 7) * 8;
    char* const bW1 = bW0 + 64 * ROWB;
    char* const bW2 = bW0 + 128 * ROWB;
    char* const bW3 = bW0 + 192 * ROWB;

    // ---- fragment-read offsets (A-layout: row = lane&31, k = (lane>>5)*8 + j)
    const int aR0 = (wm + (lane & 31)) * ROWB + (lane >> 5) * 16;  // + ks*32
    const int aR1 = aR0 + 32 * ROWB;
    const int bR0 = (wn + (lane & 31)) * ROWB + (lane >> 5) * 16;
    const int bR1 = bR0 + 32 * ROWB;

    f32x16 acc00 = {0.f}, acc01 = {0.f}, acc10 = {0.f}, acc11 = {0.f};

    // prologue: tile 0 into registers
    f32x4 ra0 = *(const f32x4*)(aBase);
    f32x4 ra1 = *(const f32x4*)(aBase + rstep);
    f32x4 rb0 = *(const f32x4*)(bBase);
    f32x4 rb1 = *(const f32x4*)(bBase + rstep);
    f32x4 rb2 = *(const f32x4*)(bBase + 2 * rstep);
    f32x4 rb3 = *(const f32x4*)(bBase + 3 * rstep);

#pragma unroll 2
    for (int T = 0; T < NS; ++T) {
        if (T)  // all waves consumed tile T-1 frags (MFMA data-deps) -> plain barrier
            asm volatile("s_barrier" ::: "memory");

        // publish tile T (compiler inserts the vmcnt wait for ra*/rb* here)
        *(uint2*)aW0 = make_uint2(cvt_pk_bf16(ra0.x, ra0.y), cvt_pk_bf16(ra0.z, ra0.w));
        *(uint2*)aW1 = make_uint2(cvt_pk_bf16(ra1.x, ra1.y), cvt_pk_bf16(ra1.z, ra1.w));
        *(uint2*)bW0 = make_uint2(cvt_pk_bf16(rb0.x, rb0.y), cvt_pk_bf16(rb0.z, rb0.w));
        *(uint2*)bW1 = make_uint2(cvt_pk_bf16(rb1.x, rb1.y), cvt_pk_bf16(rb1.z, rb1.w));
        *(uint2*)bW2 = make_uint2(cvt_pk_bf16(rb2.x, rb2.y), cvt_pk_bf16(rb2.z, rb2.w));
        *(uint2*)bW3 = make_uint2(cvt_pk_bf16(rb3.x, rb3.y), cvt_pk_bf16(rb3.z, rb3.w));

        // issue tile T+1 loads; they fly across barrier + frag reads + MFMAs
        if (T + 1 < NS) {
            const float* ap = aBase + (T + 1) * BK;
            const float* bp = bBase + (T + 1) * BK;
            ra0 = *(const f32x4*)(ap);
            ra1 = *(const f32x4*)(ap + rstep);
            rb0 = *(const f32x4*)(bp);
            rb1 = *(const f32x4*)(bp + rstep);
            rb2 = *(const f32x4*)(bp + 2 * rstep);
            rb3 = *(const f32x4*)(bp + 3 * rstep);
        }

        // writes visible to block; vmcnt NOT drained
        asm volatile("s_waitcnt lgkmcnt(0)" ::: "memory");
        __builtin_amdgcn_s_barrier();

#pragma unroll
        for (int ks = 0; ks < 2; ++ks) {
            const int kb = ks * 32;
            s16x8 a0 = *(const s16x8*)((const char*)As + aR0 + kb);
            s16x8 a1 = *(const s16x8*)((const char*)As + aR1 + kb);
            s16x8 b0 = *(const s16x8*)((const char*)Bs + bR0 + kb);
            s16x8 b1 = *(const s16x8*)((const char*)Bs + bR1 + kb);
            acc00 = __builtin_amdgcn_mfma_f32_32x32x16_bf16(a0, b0, acc00, 0, 0, 0);
            acc01 = __builtin_amdgcn_mfma_f32_32x32x16_bf16(a0, b1, acc01, 0, 0, 0);
            acc10 = __builtin_amdgcn_mfma_f32_32x32x16_bf16(a1, b0, acc10, 0, 0, 0);
            acc11 = __builtin_amdgcn_mfma_f32_32x32x16_bf16(a1, b1, acc11, 0, 0, 0);
        }
    }

    // epilogue: C/D map col=lane&31, row=(reg&3)+8*(reg>>2)+4*(lane>>5)
    float* outp = partials + (size_t)k * (NROW * NROW);
    const int ccol = wn + (lane & 31);
    const int rb   = h * 128 + wm + (lane >> 5) * 4;
#pragma unroll
    for (int r = 0; r < 16; ++r) {
        const int crow = rb + (r & 3) + 8 * (r >> 2);
        float* rowp = outp + (size_t)crow * NROW + ccol;
        __builtin_nontemporal_store(acc00[r], rowp);
        __builtin_nontemporal_store(acc01[r], rowp + 32);
        __builtin_nontemporal_store(acc10[r], rowp + 32 * NROW);
        __builtin_nontemporal_store(acc11[r], rowp + 32 * NROW + 32);
    }
}

// Stage 2: reduce partials over split; per-row masked exp, rowsum, pos, rowloss; store E.
__global__ __launch_bounds__(NROW) void reduce_loss_rows(
    const float* __restrict__ partials, const int* __restrict__ idx,
    float* __restrict__ E, float* __restrict__ rowloss, float* __restrict__ posbuf)
{
    const int b = blockIdx.x;   // row
    const int t = threadIdx.x;  // col
    const float* p = partials + b * NROW + t;
    float sum = 0.f;
#pragma unroll 8
    for (int s = 0; s < SPLIT; ++s)
        sum += p[(size_t)s * (NROW * NROW)];

    const float logit = sum * TEMP;
    const bool  mask  = (idx[b] != idx[t]) || (b == t);
    const float e     = mask ? expf(logit) : 0.0f;
    E[b * NROW + t] = e;

    __shared__ float red[NROW];
    __shared__ float posv;
    if (t == b) posv = logit;
    red[t] = e;
    __syncthreads();
#pragma unroll
    for (int s = NROW / 2; s > 0; s >>= 1) {
        if (t < s) red[t] += red[t + s];
        __syncthreads();
    }
    if (t == 0) {
        posbuf[b]  = posv;
        rowloss[b] = logf(red[0]) - posv;
    }
}

// Stage 3: column sums of E, column losses, final mean.
__global__ __launch_bounds__(NROW) void finalize_loss(
    const float* __restrict__ E, const float* __restrict__ rowloss,
    const float* __restrict__ posbuf, float* __restrict__ out)
{
    const int t = threadIdx.x;
    float csum = 0.f;
#pragma unroll 8
    for (int i = 0; i < NROW; ++i)
        csum += E[i * NROW + t];
    const float closs = logf(csum) - posbuf[t];
    const float rl    = rowloss[t];

    __shared__ float redc[NROW];
    __shared__ float redr[NROW];
    redc[t] = closs;
    redr[t] = rl;
    __syncthreads();
#pragma unroll
    for (int s = NROW / 2; s > 0; s >>= 1) {
        if (t < s) { redc[t] += redc[t + s]; redr[t] += redr[t + s]; }
        __syncthreads();
    }
    if (t == 0)
        out[0] = 0.5f * (redc[0] + redr[0]) * (1.0f / (float)NROW);
}

extern "C" void kernel_launch(void* const* d_in, const int* in_sizes, int n_in,
                              void* d_out, int out_size, void* d_ws, size_t ws_size,
                              hipStream_t stream)
{
    (void)in_sizes; (void)n_in; (void)out_size; (void)ws_size;
    const float* A   = (const float*)d_in[0];
    const float* Bm  = (const float*)d_in[1];
    const int*   idx = (const int*)d_in[2];
    float*       out = (float*)d_out;

    float* partials = (float*)d_ws;                       // 64 MB (split=256)
    float* E        = partials + (size_t)SPLIT * NROW * NROW;
    float* rowloss  = E + NROW * NROW;
    float* posbuf   = rowloss + NROW;

    gemm_half2<<<SPLIT * 2, TPB, 0, stream>>>(A, Bm, partials);
    reduce_loss_rows<<<NROW, NROW, 0, stream>>>(partials, idx, E, rowloss, posbuf);
    finalize_loss<<<1, NROW, 0, stream>>>(E, rowloss, posbuf, out);
}